// Round 4
// baseline (958.239 us; speedup 1.0000x reference)
//
#include <hip/hip_runtime.h>
#include <hip/hip_bf16.h>
#include <math.h>

#define N_NODES 100000
#define N_EDGES 1600000
#define F 128
#define OUT_C 64
#define NUM_CLASSES 40
#define BN_EPS 1e-5f

#define NBUCK 782  // ceil(100000/128) buckets of 128 destination nodes
#define BCAP 4096  // per-bucket edge capacity (mean 2046, ~32 sigma margin)

typedef __hip_bfloat16 bf16;

// ---- fp32 param block offsets ----
#define PW1 0
#define PB1 16384
#define PW2 16512
#define PB2 32896
#define PGAMMA 33024
#define PBETA 33152
#define PMEAN 33280
#define PVAR 33408
#define PCLSW 33536
#define PCLSB 41728
#define PSIMW 41792
#define PSIMB 46912
#define PHOMW 46952
#define PHOMB 47080
#define PENTW 47081
#define PENTB 47209
#define PRAW_TOTAL 47210
#define PFW 47232
#define PFB 63616
#define PTOTAL 63744

__device__ __forceinline__ float uasf(unsigned u) { return __uint_as_float(u); }
__device__ __forceinline__ unsigned f2bu(float f) {
    bf16 h = __float2bfloat16(f);
    return (unsigned)*(unsigned short*)&h;
}

// ---------------- dtype detection ----------------
__global__ void detect_kernel(const void* __restrict__ x, const void* __restrict__ ei,
                              int* __restrict__ flags) {
    if (blockIdx.x != 0 || threadIdx.x != 0) return;
    const unsigned* xw = (const unsigned*)x;
    int votes = 0;
    for (int i = 0; i < 64; i++) {
        unsigned w = xw[i];
        unsigned e = (w >> 23) & 0xFFu;
        if (w == 0u || (e >= 90u && e <= 160u)) votes++;
    }
    flags[0] = (votes >= 48) ? 1 : 0;
    const unsigned* ew = (const unsigned*)ei;
    int zero_odd = 0;
    for (int i = 0; i < 64; i++)
        if (ew[2 * i + 1] == 0u) zero_odd++;
    flags[1] = (zero_odd >= 60) ? 1 : 0;
}

// ---------------- consolidated param convert ----------------
struct ParamSegs {
    const void* src[16];
    int dst[16];
};

__global__ void cvtparams_kernel(ParamSegs segs, float* __restrict__ params,
                                 const int* __restrict__ flags) {
    int idx = blockIdx.x * 256 + threadIdx.x;
    if (idx >= PRAW_TOTAL) return;
    int k = 0;
#pragma unroll
    for (int s = 1; s < 16; s++)
        if (idx >= segs.dst[s]) k = s;
    int rel = idx - segs.dst[k];
    const void* sp = segs.src[k];
    float v = flags[0] ? ((const float*)sp)[rel]
                       : __bfloat162float(((const bf16*)sp)[rel]);
    params[idx] = v;
}

// ---------------- edge load ----------------
__device__ __forceinline__ int load_edge(const int* __restrict__ ei, int which, int i, int i64) {
    size_t elem = (size_t)which * N_EDGES + (size_t)i;
    return i64 ? ei[elem * 2] : ei[elem];
}

// ---------------- fill: node hist + bucket append (one edge pass) ----------------
__global__ void fill1_kernel(const int* __restrict__ ei, int* __restrict__ counts,
                             int* __restrict__ bcur, int* __restrict__ srcBuck,
                             const int* __restrict__ flags) {
    int i = blockIdx.x * blockDim.x + threadIdx.x;
    if (i >= N_EDGES) return;
    int i64 = flags[1];
    int c = load_edge(ei, 1, i, i64);
    int r = load_edge(ei, 0, i, i64);
    atomicAdd(&counts[c], 1);
    int b = c >> 7;
    int p = atomicAdd(&bcur[b], 1);
    if (p < BCAP) srcBuck[b * BCAP + p] = ((c & 127) << 17) | r;
}

__global__ void dinv_kernel(const int* __restrict__ counts, float* __restrict__ dinv, int n) {
    int i = blockIdx.x * blockDim.x + threadIdx.x;
    if (i < n) dinv[i] = rsqrtf((float)(counts[i] + 1));
}

// ---------------- x -> bf16 prescaled by dinv ----------------
__global__ void cvtx_kernel(const void* __restrict__ x, const float* __restrict__ dinv,
                            unsigned short* __restrict__ B16, const int* __restrict__ flags) {
    int i4 = blockIdx.x * blockDim.x + threadIdx.x;  // float4 index
    if (i4 >= N_NODES * F / 4) return;
    int n = i4 >> 5;
    float d = dinv[n];
    float v0, v1, v2, v3;
    if (flags[0]) {
        float4 v = ((const float4*)x)[i4];
        v0 = v.x; v1 = v.y; v2 = v.z; v3 = v.w;
    } else {
        uint2 u = ((const uint2*)x)[i4];
        v0 = uasf(u.x << 16);
        v1 = uasf(u.x & 0xFFFF0000u);
        v2 = uasf(u.y << 16);
        v3 = uasf(u.y & 0xFFFF0000u);
    }
    uint2 o;
    o.x = f2bu(v0 * d) | (f2bu(v1 * d) << 16);
    o.y = f2bu(v2 * d) | (f2bu(v3 * d) << 16);
    ((uint2*)B16)[i4] = o;
}

// ---------------- fused W2 @ [cls|sim|hom|ent] precompute ----------------
__device__ __forceinline__ float headw(const float* __restrict__ p, int j, int c) {
    if (c < OUT_C) return p[PCLSW + j * OUT_C + c];
    if (c < OUT_C + NUM_CLASSES) return p[PSIMW + j * NUM_CLASSES + (c - OUT_C)];
    if (c == 104) return p[PHOMW + j];
    if (c == 105) return p[PENTW + j];
    return 0.f;
}

__global__ void fusew_kernel(float* __restrict__ params) {
    int idx = blockIdx.x * 256 + threadIdx.x;
    int k = idx >> 7;
    int c = idx & 127;
    float s = 0.f;
    for (int j = 0; j < 128; j++) s += params[PW2 + k * 128 + j] * headw(params, j, c);
    params[PFW + k * 128 + c] = s;
    if (k == 0) {
        float b = 0.f;
        for (int j = 0; j < 128; j++) b += params[PB2 + j] * headw(params, j, c);
        if (c < OUT_C) b += params[PCLSB + c];
        else if (c < OUT_C + NUM_CLASSES) b += params[PSIMB + c - OUT_C];
        else if (c == 104) b += params[PHOMB];
        else if (c == 105) b += params[PENTB];
        params[PFB + c] = b;
    }
}

// ---------------- Aggregation: LDS counting sort per bucket + gather ----------------
// out[n] = dinv[n] * ( sum_edges bf16row(src) + bf16row(n) )   [rows prescaled by dinv(src)]
__global__ __launch_bounds__(256) void agg_kernel(const unsigned short* __restrict__ B16,
                                                  float* __restrict__ outSB,
                                                  const int* __restrict__ srcBuck,
                                                  const int* __restrict__ bcur,
                                                  const float* __restrict__ dinv) {
    __shared__ int raw[BCAP];
    __shared__ int sorted[BCAP];
    __shared__ int dcnt[128], doff[128], dcur[128];
    int b = blockIdx.x;
    int t = threadIdx.x;
    int cnt = bcur[b];
    if (cnt > BCAP) cnt = BCAP;
    if (t < 128) dcnt[t] = 0;
    __syncthreads();
    for (int i = t; i < cnt; i += 256) {
        int e = srcBuck[b * BCAP + i];
        raw[i] = e;
        atomicAdd(&dcnt[e >> 17], 1);
    }
    __syncthreads();
    if (t < 128) doff[t] = dcnt[t];
    __syncthreads();
    for (int d = 1; d < 128; d <<= 1) {
        int add = 0;
        if (t < 128 && t >= d) add = doff[t - d];
        __syncthreads();
        if (t < 128) doff[t] += add;
        __syncthreads();
    }
    if (t < 128) {
        doff[t] -= dcnt[t];  // exclusive
        dcur[t] = 0;
    }
    __syncthreads();
    for (int i = t; i < cnt; i += 256) {
        int e = raw[i];
        int d = e >> 17;
        int r = atomicAdd(&dcur[d], 1);
        sorted[doff[d] + r] = e & 0x1FFFF;
    }
    __syncthreads();

    int hl4 = (t & 31) << 2;  // ushort offset within row
    int base = b << 7;
    for (int d = t >> 5; d < 128; d += 8) {
        int n = base + d;
        if (n >= N_NODES) break;
        float a0, a1, a2, a3;
        {  // self row (prescaled by dinv[n] already)
            uint2 u = *(const uint2*)(B16 + ((size_t)n << 7) + hl4);
            a0 = uasf(u.x << 16);
            a1 = uasf(u.x & 0xFFFF0000u);
            a2 = uasf(u.y << 16);
            a3 = uasf(u.y & 0xFFFF0000u);
        }
        int o = doff[d], k = dcnt[d];
        int j = 0;
        for (; j + 2 <= k; j += 2) {
            int s0 = sorted[o + j];
            int s1 = sorted[o + j + 1];
            uint2 u0 = *(const uint2*)(B16 + ((size_t)s0 << 7) + hl4);
            uint2 u1 = *(const uint2*)(B16 + ((size_t)s1 << 7) + hl4);
            a0 += uasf(u0.x << 16) + uasf(u1.x << 16);
            a1 += uasf(u0.x & 0xFFFF0000u) + uasf(u1.x & 0xFFFF0000u);
            a2 += uasf(u0.y << 16) + uasf(u1.y << 16);
            a3 += uasf(u0.y & 0xFFFF0000u) + uasf(u1.y & 0xFFFF0000u);
        }
        if (j < k) {
            int s0 = sorted[o + j];
            uint2 u0 = *(const uint2*)(B16 + ((size_t)s0 << 7) + hl4);
            a0 += uasf(u0.x << 16);
            a1 += uasf(u0.x & 0xFFFF0000u);
            a2 += uasf(u0.y << 16);
            a3 += uasf(u0.y & 0xFFFF0000u);
        }
        float dn = dinv[n];
        float4 o4 = make_float4(a0 * dn, a1 * dn, a2 * dn, a3 * dn);
        *(float4*)&outSB[((size_t)n << 7) + hl4] = o4;
    }
}

// ---------------- GEMM: C[nrows x 128] = A @ W + bias; mode1: BN+ReLU+prescale->bf16 ----
#define ATPITCH 68

__global__ __launch_bounds__(256) void gemm_kernel(const float* __restrict__ A,
                                                   const float* __restrict__ Wg,
                                                   float* __restrict__ Cf,
                                                   unsigned short* __restrict__ Cb,
                                                   const float* __restrict__ params,
                                                   const float* __restrict__ dinv,
                                                   int bias_off, int mode, int nrows) {
    __shared__ float At[128 * ATPITCH];
    int row0 = blockIdx.x * 64;
    int t = threadIdx.x;
    int rows_here = nrows - row0;
    if (rows_here > 64) rows_here = 64;
#pragma unroll
    for (int it = 0; it < 8; it++) {
        int idx4 = it * 256 + t;
        int r = idx4 >> 5;
        int c4 = (idx4 & 31) << 2;
        float4 v = make_float4(0.f, 0.f, 0.f, 0.f);
        if (r < rows_here) v = *(const float4*)&A[(size_t)(row0 + r) * 128 + c4];
        At[(c4 + 0) * ATPITCH + r] = v.x;
        At[(c4 + 1) * ATPITCH + r] = v.y;
        At[(c4 + 2) * ATPITCH + r] = v.z;
        At[(c4 + 3) * ATPITCH + r] = v.w;
    }
    __syncthreads();

    int rg = (t & 15) << 2;
    int cg = (t >> 4) << 3;
    float acc[4][8];
#pragma unroll
    for (int i = 0; i < 4; i++)
#pragma unroll
        for (int j = 0; j < 8; j++) acc[i][j] = 0.f;

#pragma unroll 4
    for (int k = 0; k < 128; k++) {
        float4 a = *(const float4*)&At[k * ATPITCH + rg];
        float4 w0 = *(const float4*)&Wg[k * 128 + cg];
        float4 w1 = *(const float4*)&Wg[k * 128 + cg + 4];
        float aa[4] = {a.x, a.y, a.z, a.w};
        float ww[8] = {w0.x, w0.y, w0.z, w0.w, w1.x, w1.y, w1.z, w1.w};
#pragma unroll
        for (int i = 0; i < 4; i++)
#pragma unroll
            for (int j = 0; j < 8; j++) acc[i][j] += aa[i] * ww[j];
    }

    float bias[8], scale[8], shift[8];
#pragma unroll
    for (int j = 0; j < 8; j++) {
        int c = cg + j;
        bias[j] = params[bias_off + c];
        if (mode) {
            float s = rsqrtf(params[PVAR + c] + BN_EPS) * params[PGAMMA + c];
            scale[j] = s;
            shift[j] = params[PBETA + c] - params[PMEAN + c] * s;
        }
    }
#pragma unroll
    for (int i = 0; i < 4; i++) {
        int r = row0 + rg + i;
        if (r < nrows) {
            if (mode) {
                float dsc = dinv[r];
                unsigned p[4];
#pragma unroll
                for (int j = 0; j < 4; j++) {
                    float v0 = fmaxf((acc[i][2 * j] + bias[2 * j]) * scale[2 * j] + shift[2 * j], 0.f) * dsc;
                    float v1 = fmaxf((acc[i][2 * j + 1] + bias[2 * j + 1]) * scale[2 * j + 1] + shift[2 * j + 1], 0.f) * dsc;
                    p[j] = f2bu(v0) | (f2bu(v1) << 16);
                }
                uint4 pk = make_uint4(p[0], p[1], p[2], p[3]);
                *(uint4*)&Cb[(size_t)r * 128 + cg] = pk;
            } else {
                float o[8];
#pragma unroll
                for (int j = 0; j < 8; j++) o[j] = acc[i][j] + bias[j];
                *(float4*)&Cf[(size_t)r * 128 + cg] = make_float4(o[0], o[1], o[2], o[3]);
                *(float4*)&Cf[(size_t)r * 128 + cg + 4] = make_float4(o[4], o[5], o[6], o[7]);
            }
        }
    }
}

// ---------------- Postprocess ----------------
__global__ __launch_bounds__(256) void post_kernel(const float* __restrict__ L,
                                                   void* __restrict__ out,
                                                   const int* __restrict__ flags) {
    int isf = flags[0];
    int wave = threadIdx.x >> 6;
    int lane = threadIdx.x & 63;
    int n = blockIdx.x * 4 + wave;
    if (n >= N_NODES) return;
    const float* row = L + (size_t)n * 128;
    float a = row[lane];
    float sv = (lane < NUM_CLASSES) ? row[OUT_C + lane] : -INFINITY;

    const size_t OFF_SIM = (size_t)N_NODES * OUT_C;
    const size_t OFF_HOM = OFF_SIM + (size_t)N_NODES * NUM_CLASSES;
    const size_t OFF_ENT = OFF_HOM + (size_t)N_NODES;
    float* outf = (float*)out;
    bf16* outb = (bf16*)out;
#define STORE_OUT(idx, v)                        \
    do {                                         \
        if (isf) outf[(idx)] = (v);              \
        else outb[(idx)] = __float2bfloat16(v);  \
    } while (0)

    if (lane == 0) {
        STORE_OUT(OFF_HOM + n, 1.f / (1.f + expf(-row[104])));
        STORE_OUT(OFF_ENT + n, 1.f / (1.f + expf(-row[105])));
    }
    float m = a;
#pragma unroll
    for (int d = 32; d > 0; d >>= 1) m = fmaxf(m, __shfl_xor(m, d));
    float ex = expf(a - m);
    float S = ex;
#pragma unroll
    for (int d = 32; d > 0; d >>= 1) S += __shfl_xor(S, d);
    STORE_OUT((size_t)n * OUT_C + lane, a - m - logf(S));
    float ms = sv;
#pragma unroll
    for (int d = 32; d > 0; d >>= 1) ms = fmaxf(ms, __shfl_xor(ms, d));
    float es = (lane < NUM_CLASSES) ? expf(sv - ms) : 0.f;
    float Ss = es;
#pragma unroll
    for (int d = 32; d > 0; d >>= 1) Ss += __shfl_xor(Ss, d);
    if (lane < NUM_CLASSES) STORE_OUT(OFF_SIM + (size_t)n * NUM_CLASSES + lane, es / Ss);
#undef STORE_OUT
}

// ---------------- Launch ----------------
extern "C" void kernel_launch(void* const* d_in, const int* in_sizes, int n_in,
                              void* d_out, int out_size, void* d_ws, size_t ws_size,
                              hipStream_t stream) {
    const void* x = d_in[0];
    const int* ei = (const int*)d_in[1];

    char* ws = (char*)d_ws;
    size_t o = 0;
    auto alloc = [&](size_t bytes) {
        size_t r = o;
        o = (o + bytes + 255) & ~(size_t)255;
        return r;
    };
    float* SA = (float*)(ws + alloc((size_t)N_NODES * F * 4));  // logits (late); early: srcBuck+B16
    float* SB = (float*)(ws + alloc((size_t)N_NODES * F * 4));
    float* params = (float*)(ws + alloc((size_t)PTOTAL * 4));
    float* dinv = (float*)(ws + alloc((size_t)N_NODES * 4));
    int* counts = (int*)(ws + alloc((size_t)N_NODES * 4));
    int* bcur = (int*)(ws + alloc((size_t)(NBUCK + 8) * 4));
    int* flags = (int*)(ws + alloc(256));

    // aliases inside SA (dead before gemm2 writes SA)
    int* srcBuck = (int*)SA;                                           // 12.81 MB
    unsigned short* B16 = (unsigned short*)((char*)SA + 13u * 1024 * 1024);  // 25.6 MB

    detect_kernel<<<1, 64, 0, stream>>>(x, ei, flags);
    hipMemsetAsync(counts, 0, (size_t)N_NODES * 4, stream);
    hipMemsetAsync(bcur, 0, (size_t)(NBUCK + 8) * 4, stream);

    // params -> fp32 block (single kernel)
    ParamSegs segs;
    const int srcIdx[16] = {2, 3, 4, 5, 6, 7, 8, 9, 10, 11, 12, 13, 14, 15, 16, 17};
    const int dsts[16] = {PW1, PB1, PW2, PB2, PGAMMA, PBETA, PMEAN, PVAR,
                          PCLSW, PCLSB, PSIMW, PSIMB, PHOMW, PHOMB, PENTW, PENTB};
    for (int k = 0; k < 16; k++) {
        segs.src[k] = d_in[srcIdx[k]];
        segs.dst[k] = dsts[k];
    }
    cvtparams_kernel<<<(PRAW_TOTAL + 255) / 256, 256, 0, stream>>>(segs, params, flags);
    fusew_kernel<<<64, 256, 0, stream>>>(params);

    // graph structure: hist + bucket append, then dinv
    fill1_kernel<<<(N_EDGES + 255) / 256, 256, 0, stream>>>(ei, counts, bcur, srcBuck, flags);
    dinv_kernel<<<(N_NODES + 255) / 256, 256, 0, stream>>>(counts, dinv, N_NODES);

    // x -> bf16 prescaled
    cvtx_kernel<<<(N_NODES * F / 4 + 255) / 256, 256, 0, stream>>>(x, dinv, B16, flags);

    const int gemmGrid = (N_NODES + 63) / 64;

    // layer 1: g1 = A_hat x ; h1 = bf16(ReLU(BN(g1 @ W1 + b1)) * dinv)
    agg_kernel<<<NBUCK, 256, 0, stream>>>(B16, SB, srcBuck, bcur, dinv);
    gemm_kernel<<<gemmGrid, 256, 0, stream>>>(SB, params + PW1, nullptr, B16, params, dinv,
                                              PB1, 1, N_NODES);
    // layer 2 + fused heads: g2 = A_hat h1 ; logits = g2 @ Wfuse + bfuse
    agg_kernel<<<NBUCK, 256, 0, stream>>>(B16, SB, srcBuck, bcur, dinv);
    gemm_kernel<<<gemmGrid, 256, 0, stream>>>(SB, params + PFW, SA, nullptr, params, dinv,
                                              PFB, 0, N_NODES);
    // postprocess
    post_kernel<<<(N_NODES + 3) / 4, 256, 0, stream>>>(SA, d_out, flags);
}

// Round 5
// 581.985 us; speedup vs baseline: 1.6465x; 1.6465x over previous
//
#include <hip/hip_runtime.h>
#include <hip/hip_bf16.h>
#include <math.h>

#define N_NODES 100000
#define N_EDGES 1600000
#define F 128
#define OUT_C 64
#define NUM_CLASSES 40
#define BN_EPS 1e-5f

#define NBUCK 782   // ceil(100000/128) buckets of 128 destination nodes
#define BCAP 4096   // per-bucket edge capacity (mean 2046, ~45 sigma margin)
#define FILL_BLOCKS 128
#define EPB ((N_EDGES + FILL_BLOCKS - 1) / FILL_BLOCKS)  // 12500

typedef __hip_bfloat16 bf16;

// ---- fp32 param block offsets ----
#define PW1 0
#define PB1 16384
#define PW2 16512
#define PB2 32896
#define PGAMMA 33024
#define PBETA 33152
#define PMEAN 33280
#define PVAR 33408
#define PCLSW 33536
#define PCLSB 41728
#define PSIMW 41792
#define PSIMB 46912
#define PHOMW 46952
#define PHOMB 47080
#define PENTW 47081
#define PENTB 47209
#define PRAW_TOTAL 47210
#define PFW 47232
#define PFB 63616
#define PTOTAL 63744

__device__ __forceinline__ float uasf(unsigned u) { return __uint_as_float(u); }
__device__ __forceinline__ unsigned f2bu(float f) {
    bf16 h = __float2bfloat16(f);
    return (unsigned)*(unsigned short*)&h;
}

// ---------------- dtype detection ----------------
__global__ void detect_kernel(const void* __restrict__ x, const void* __restrict__ ei,
                              int* __restrict__ flags) {
    if (blockIdx.x != 0 || threadIdx.x != 0) return;
    const unsigned* xw = (const unsigned*)x;
    int votes = 0;
    for (int i = 0; i < 64; i++) {
        unsigned w = xw[i];
        unsigned e = (w >> 23) & 0xFFu;
        if (w == 0u || (e >= 90u && e <= 160u)) votes++;
    }
    flags[0] = (votes >= 48) ? 1 : 0;
    const unsigned* ew = (const unsigned*)ei;
    int zero_odd = 0;
    for (int i = 0; i < 64; i++)
        if (ew[2 * i + 1] == 0u) zero_odd++;
    flags[1] = (zero_odd >= 60) ? 1 : 0;
}

// ---------------- consolidated param convert ----------------
struct ParamSegs {
    const void* src[16];
    int dst[16];
};

__global__ void cvtparams_kernel(ParamSegs segs, float* __restrict__ params,
                                 const int* __restrict__ flags) {
    int idx = blockIdx.x * 256 + threadIdx.x;
    if (idx >= PRAW_TOTAL) return;
    int k = 0;
#pragma unroll
    for (int s = 1; s < 16; s++)
        if (idx >= segs.dst[s]) k = s;
    int rel = idx - segs.dst[k];
    const void* sp = segs.src[k];
    float v = flags[0] ? ((const float*)sp)[rel]
                       : __bfloat162float(((const bf16*)sp)[rel]);
    params[idx] = v;
}

// ---------------- edge load ----------------
__device__ __forceinline__ int load_edge(const int* __restrict__ ei, int which, int i, int i64) {
    size_t elem = (size_t)which * N_EDGES + (size_t)i;
    return i64 ? ei[elem * 2] : ei[elem];
}

// ---------------- fill: block-local LDS hist -> one reservation per (block,bucket) ----------
__global__ __launch_bounds__(256) void fill2_kernel(const int* __restrict__ ei,
                                                    int* __restrict__ bcur,
                                                    int* __restrict__ srcBuck,
                                                    const int* __restrict__ flags) {
    __shared__ int hist[NBUCK];
    __shared__ int gbase[NBUCK];
    __shared__ int lcur[NBUCK];
    int blk = blockIdx.x;
    int t = threadIdx.x;
    int i64 = flags[1];
    int e0 = blk * EPB;
    int ecnt = N_EDGES - e0;
    if (ecnt > EPB) ecnt = EPB;
    for (int i = t; i < NBUCK; i += 256) hist[i] = 0;
    __syncthreads();
    // phase A: per-bucket histogram (LDS atomics)
    for (int i = t; i < ecnt; i += 256) {
        int c = load_edge(ei, 1, e0 + i, i64);
        atomicAdd(&hist[c >> 7], 1);
    }
    __syncthreads();
    // phase B: one global reservation per non-empty bucket
    for (int i = t; i < NBUCK; i += 256) {
        int c = hist[i];
        gbase[i] = (c > 0) ? atomicAdd(&bcur[i], c) : 0;
        lcur[i] = 0;
    }
    __syncthreads();
    // phase C: scatter into this block's contiguous run (dense 64B lines)
    for (int i = t; i < ecnt; i += 256) {
        int c = load_edge(ei, 1, e0 + i, i64);
        int r = load_edge(ei, 0, e0 + i, i64);
        int b = c >> 7;
        int p = gbase[b] + atomicAdd(&lcur[b], 1);
        if (p < BCAP) srcBuck[b * BCAP + p] = ((c & 127) << 17) | r;
    }
}

// ---------------- per-bucket degree count -> dinv ----------------
__global__ __launch_bounds__(256) void bucketcnt_kernel(const int* __restrict__ srcBuck,
                                                        const int* __restrict__ bcur,
                                                        float* __restrict__ dinv) {
    __shared__ int dcnt[128];
    int b = blockIdx.x;
    int t = threadIdx.x;
    if (t < 128) dcnt[t] = 0;
    __syncthreads();
    int cnt = bcur[b];
    if (cnt > BCAP) cnt = BCAP;
    for (int i = t; i < cnt; i += 256) atomicAdd(&dcnt[srcBuck[b * BCAP + i] >> 17], 1);
    __syncthreads();
    if (t < 128) {
        int n = (b << 7) + t;
        if (n < N_NODES) dinv[n] = rsqrtf((float)(dcnt[t] + 1));
    }
}

// ---------------- x -> bf16 prescaled by dinv ----------------
__global__ void cvtx_kernel(const void* __restrict__ x, const float* __restrict__ dinv,
                            unsigned short* __restrict__ B16, const int* __restrict__ flags) {
    int i4 = blockIdx.x * blockDim.x + threadIdx.x;  // float4 index
    if (i4 >= N_NODES * F / 4) return;
    int n = i4 >> 5;
    float d = dinv[n];
    float v0, v1, v2, v3;
    if (flags[0]) {
        float4 v = ((const float4*)x)[i4];
        v0 = v.x; v1 = v.y; v2 = v.z; v3 = v.w;
    } else {
        uint2 u = ((const uint2*)x)[i4];
        v0 = uasf(u.x << 16);
        v1 = uasf(u.x & 0xFFFF0000u);
        v2 = uasf(u.y << 16);
        v3 = uasf(u.y & 0xFFFF0000u);
    }
    uint2 o;
    o.x = f2bu(v0 * d) | (f2bu(v1 * d) << 16);
    o.y = f2bu(v2 * d) | (f2bu(v3 * d) << 16);
    ((uint2*)B16)[i4] = o;
}

// ---------------- fused W2 @ [cls|sim|hom|ent] precompute ----------------
__device__ __forceinline__ float headw(const float* __restrict__ p, int j, int c) {
    if (c < OUT_C) return p[PCLSW + j * OUT_C + c];
    if (c < OUT_C + NUM_CLASSES) return p[PSIMW + j * NUM_CLASSES + (c - OUT_C)];
    if (c == 104) return p[PHOMW + j];
    if (c == 105) return p[PENTW + j];
    return 0.f;
}

__global__ void fusew_kernel(float* __restrict__ params) {
    int idx = blockIdx.x * 256 + threadIdx.x;
    int k = idx >> 7;
    int c = idx & 127;
    float s = 0.f;
    for (int j = 0; j < 128; j++) s += params[PW2 + k * 128 + j] * headw(params, j, c);
    params[PFW + k * 128 + c] = s;
    if (k == 0) {
        float b = 0.f;
        for (int j = 0; j < 128; j++) b += params[PB2 + j] * headw(params, j, c);
        if (c < OUT_C) b += params[PCLSB + c];
        else if (c < OUT_C + NUM_CLASSES) b += params[PSIMB + c - OUT_C];
        else if (c == 104) b += params[PHOMB];
        else if (c == 105) b += params[PENTB];
        params[PFB + c] = b;
    }
}

// ---------------- Aggregation: LDS counting sort per bucket + gather ----------------
__global__ __launch_bounds__(256) void agg_kernel(const unsigned short* __restrict__ B16,
                                                  float* __restrict__ outSB,
                                                  const int* __restrict__ srcBuck,
                                                  const int* __restrict__ bcur,
                                                  const float* __restrict__ dinv) {
    __shared__ int raw[BCAP];
    __shared__ int sorted[BCAP];
    __shared__ int dcnt[128], doff[128], dcur[128];
    int b = blockIdx.x;
    int t = threadIdx.x;
    int cnt = bcur[b];
    if (cnt > BCAP) cnt = BCAP;
    if (t < 128) dcnt[t] = 0;
    __syncthreads();
    for (int i = t; i < cnt; i += 256) {
        int e = srcBuck[b * BCAP + i];
        raw[i] = e;
        atomicAdd(&dcnt[e >> 17], 1);
    }
    __syncthreads();
    if (t < 128) doff[t] = dcnt[t];
    __syncthreads();
    for (int d = 1; d < 128; d <<= 1) {
        int add = 0;
        if (t < 128 && t >= d) add = doff[t - d];
        __syncthreads();
        if (t < 128) doff[t] += add;
        __syncthreads();
    }
    if (t < 128) {
        doff[t] -= dcnt[t];  // exclusive
        dcur[t] = 0;
    }
    __syncthreads();
    for (int i = t; i < cnt; i += 256) {
        int e = raw[i];
        int d = e >> 17;
        int r = atomicAdd(&dcur[d], 1);
        sorted[doff[d] + r] = e & 0x1FFFF;
    }
    __syncthreads();

    int hl4 = (t & 31) << 2;  // ushort offset within row
    int base = b << 7;
    for (int d = t >> 5; d < 128; d += 8) {
        int n = base + d;
        if (n >= N_NODES) break;
        float a0, a1, a2, a3;
        {
            uint2 u = *(const uint2*)(B16 + ((size_t)n << 7) + hl4);
            a0 = uasf(u.x << 16);
            a1 = uasf(u.x & 0xFFFF0000u);
            a2 = uasf(u.y << 16);
            a3 = uasf(u.y & 0xFFFF0000u);
        }
        int o = doff[d], k = dcnt[d];
        int j = 0;
        for (; j + 2 <= k; j += 2) {
            int s0 = sorted[o + j];
            int s1 = sorted[o + j + 1];
            uint2 u0 = *(const uint2*)(B16 + ((size_t)s0 << 7) + hl4);
            uint2 u1 = *(const uint2*)(B16 + ((size_t)s1 << 7) + hl4);
            a0 += uasf(u0.x << 16) + uasf(u1.x << 16);
            a1 += uasf(u0.x & 0xFFFF0000u) + uasf(u1.x & 0xFFFF0000u);
            a2 += uasf(u0.y << 16) + uasf(u1.y << 16);
            a3 += uasf(u0.y & 0xFFFF0000u) + uasf(u1.y & 0xFFFF0000u);
        }
        if (j < k) {
            int s0 = sorted[o + j];
            uint2 u0 = *(const uint2*)(B16 + ((size_t)s0 << 7) + hl4);
            a0 += uasf(u0.x << 16);
            a1 += uasf(u0.x & 0xFFFF0000u);
            a2 += uasf(u0.y << 16);
            a3 += uasf(u0.y & 0xFFFF0000u);
        }
        float dn = dinv[n];
        float4 o4 = make_float4(a0 * dn, a1 * dn, a2 * dn, a3 * dn);
        *(float4*)&outSB[((size_t)n << 7) + hl4] = o4;
    }
}

// ---------------- GEMM: C[nrows x 128] = A @ W + bias; mode1: BN+ReLU+prescale->bf16 ----
#define ATPITCH 68

__global__ __launch_bounds__(256) void gemm_kernel(const float* __restrict__ A,
                                                   const float* __restrict__ Wg,
                                                   float* __restrict__ Cf,
                                                   unsigned short* __restrict__ Cb,
                                                   const float* __restrict__ params,
                                                   const float* __restrict__ dinv,
                                                   int bias_off, int mode, int nrows) {
    __shared__ float At[128 * ATPITCH];
    int row0 = blockIdx.x * 64;
    int t = threadIdx.x;
    int rows_here = nrows - row0;
    if (rows_here > 64) rows_here = 64;
#pragma unroll
    for (int it = 0; it < 8; it++) {
        int idx4 = it * 256 + t;
        int r = idx4 >> 5;
        int c4 = (idx4 & 31) << 2;
        float4 v = make_float4(0.f, 0.f, 0.f, 0.f);
        if (r < rows_here) v = *(const float4*)&A[(size_t)(row0 + r) * 128 + c4];
        At[(c4 + 0) * ATPITCH + r] = v.x;
        At[(c4 + 1) * ATPITCH + r] = v.y;
        At[(c4 + 2) * ATPITCH + r] = v.z;
        At[(c4 + 3) * ATPITCH + r] = v.w;
    }
    __syncthreads();

    int rg = (t & 15) << 2;
    int cg = (t >> 4) << 3;
    float acc[4][8];
#pragma unroll
    for (int i = 0; i < 4; i++)
#pragma unroll
        for (int j = 0; j < 8; j++) acc[i][j] = 0.f;

#pragma unroll 4
    for (int k = 0; k < 128; k++) {
        float4 a = *(const float4*)&At[k * ATPITCH + rg];
        float4 w0 = *(const float4*)&Wg[k * 128 + cg];
        float4 w1 = *(const float4*)&Wg[k * 128 + cg + 4];
        float aa[4] = {a.x, a.y, a.z, a.w};
        float ww[8] = {w0.x, w0.y, w0.z, w0.w, w1.x, w1.y, w1.z, w1.w};
#pragma unroll
        for (int i = 0; i < 4; i++)
#pragma unroll
            for (int j = 0; j < 8; j++) acc[i][j] += aa[i] * ww[j];
    }

    float bias[8], scale[8], shift[8];
#pragma unroll
    for (int j = 0; j < 8; j++) {
        int c = cg + j;
        bias[j] = params[bias_off + c];
        if (mode) {
            float s = rsqrtf(params[PVAR + c] + BN_EPS) * params[PGAMMA + c];
            scale[j] = s;
            shift[j] = params[PBETA + c] - params[PMEAN + c] * s;
        }
    }
#pragma unroll
    for (int i = 0; i < 4; i++) {
        int r = row0 + rg + i;
        if (r < nrows) {
            if (mode) {
                float dsc = dinv[r];
                unsigned p[4];
#pragma unroll
                for (int j = 0; j < 4; j++) {
                    float v0 = fmaxf((acc[i][2 * j] + bias[2 * j]) * scale[2 * j] + shift[2 * j], 0.f) * dsc;
                    float v1 = fmaxf((acc[i][2 * j + 1] + bias[2 * j + 1]) * scale[2 * j + 1] + shift[2 * j + 1], 0.f) * dsc;
                    p[j] = f2bu(v0) | (f2bu(v1) << 16);
                }
                uint4 pk = make_uint4(p[0], p[1], p[2], p[3]);
                *(uint4*)&Cb[(size_t)r * 128 + cg] = pk;
            } else {
                float o[8];
#pragma unroll
                for (int j = 0; j < 8; j++) o[j] = acc[i][j] + bias[j];
                *(float4*)&Cf[(size_t)r * 128 + cg] = make_float4(o[0], o[1], o[2], o[3]);
                *(float4*)&Cf[(size_t)r * 128 + cg + 4] = make_float4(o[4], o[5], o[6], o[7]);
            }
        }
    }
}

// ---------------- Postprocess ----------------
__global__ __launch_bounds__(256) void post_kernel(const float* __restrict__ L,
                                                   void* __restrict__ out,
                                                   const int* __restrict__ flags) {
    int isf = flags[0];
    int wave = threadIdx.x >> 6;
    int lane = threadIdx.x & 63;
    int n = blockIdx.x * 4 + wave;
    if (n >= N_NODES) return;
    const float* row = L + (size_t)n * 128;
    float a = row[lane];
    float sv = (lane < NUM_CLASSES) ? row[OUT_C + lane] : -INFINITY;

    const size_t OFF_SIM = (size_t)N_NODES * OUT_C;
    const size_t OFF_HOM = OFF_SIM + (size_t)N_NODES * NUM_CLASSES;
    const size_t OFF_ENT = OFF_HOM + (size_t)N_NODES;
    float* outf = (float*)out;
    bf16* outb = (bf16*)out;
#define STORE_OUT(idx, v)                        \
    do {                                         \
        if (isf) outf[(idx)] = (v);              \
        else outb[(idx)] = __float2bfloat16(v);  \
    } while (0)

    if (lane == 0) {
        STORE_OUT(OFF_HOM + n, 1.f / (1.f + expf(-row[104])));
        STORE_OUT(OFF_ENT + n, 1.f / (1.f + expf(-row[105])));
    }
    float m = a;
#pragma unroll
    for (int d = 32; d > 0; d >>= 1) m = fmaxf(m, __shfl_xor(m, d));
    float ex = expf(a - m);
    float S = ex;
#pragma unroll
    for (int d = 32; d > 0; d >>= 1) S += __shfl_xor(S, d);
    STORE_OUT((size_t)n * OUT_C + lane, a - m - logf(S));
    float ms = sv;
#pragma unroll
    for (int d = 32; d > 0; d >>= 1) ms = fmaxf(ms, __shfl_xor(ms, d));
    float es = (lane < NUM_CLASSES) ? expf(sv - ms) : 0.f;
    float Ss = es;
#pragma unroll
    for (int d = 32; d > 0; d >>= 1) Ss += __shfl_xor(Ss, d);
    if (lane < NUM_CLASSES) STORE_OUT(OFF_SIM + (size_t)n * NUM_CLASSES + lane, es / Ss);
#undef STORE_OUT
}

// ---------------- Launch ----------------
extern "C" void kernel_launch(void* const* d_in, const int* in_sizes, int n_in,
                              void* d_out, int out_size, void* d_ws, size_t ws_size,
                              hipStream_t stream) {
    const void* x = d_in[0];
    const int* ei = (const int*)d_in[1];

    char* ws = (char*)d_ws;
    size_t o = 0;
    auto alloc = [&](size_t bytes) {
        size_t r = o;
        o = (o + bytes + 255) & ~(size_t)255;
        return r;
    };
    float* SA = (float*)(ws + alloc((size_t)N_NODES * F * 4));  // logits (late); early: srcBuck+B16
    float* SB = (float*)(ws + alloc((size_t)N_NODES * F * 4));
    float* params = (float*)(ws + alloc((size_t)PTOTAL * 4));
    float* dinv = (float*)(ws + alloc((size_t)N_NODES * 4));
    int* bcur = (int*)(ws + alloc((size_t)(NBUCK + 8) * 4));
    int* flags = (int*)(ws + alloc(256));

    // aliases inside SA (dead before gemm2 writes SA)
    int* srcBuck = (int*)SA;                                                 // 12.81 MB
    unsigned short* B16 = (unsigned short*)((char*)SA + 13u * 1024 * 1024);  // 25.6 MB

    detect_kernel<<<1, 64, 0, stream>>>(x, ei, flags);
    hipMemsetAsync(bcur, 0, (size_t)(NBUCK + 8) * 4, stream);

    // params -> fp32 block (single kernel)
    ParamSegs segs;
    const int srcIdx[16] = {2, 3, 4, 5, 6, 7, 8, 9, 10, 11, 12, 13, 14, 15, 16, 17};
    const int dsts[16] = {PW1, PB1, PW2, PB2, PGAMMA, PBETA, PMEAN, PVAR,
                          PCLSW, PCLSB, PSIMW, PSIMB, PHOMW, PHOMB, PENTW, PENTB};
    for (int k = 0; k < 16; k++) {
        segs.src[k] = d_in[srcIdx[k]];
        segs.dst[k] = dsts[k];
    }
    cvtparams_kernel<<<(PRAW_TOTAL + 255) / 256, 256, 0, stream>>>(segs, params, flags);
    fusew_kernel<<<64, 256, 0, stream>>>(params);

    // graph structure: bucketed edges, then per-node degree -> dinv
    fill2_kernel<<<FILL_BLOCKS, 256, 0, stream>>>(ei, bcur, srcBuck, flags);
    bucketcnt_kernel<<<NBUCK, 256, 0, stream>>>(srcBuck, bcur, dinv);

    // x -> bf16 prescaled
    cvtx_kernel<<<(N_NODES * F / 4 + 255) / 256, 256, 0, stream>>>(x, dinv, B16, flags);

    const int gemmGrid = (N_NODES + 63) / 64;

    // layer 1: g1 = A_hat x ; h1 = bf16(ReLU(BN(g1 @ W1 + b1)) * dinv)
    agg_kernel<<<NBUCK, 256, 0, stream>>>(B16, SB, srcBuck, bcur, dinv);
    gemm_kernel<<<gemmGrid, 256, 0, stream>>>(SB, params + PW1, nullptr, B16, params, dinv,
                                              PB1, 1, N_NODES);
    // layer 2 + fused heads: g2 = A_hat h1 ; logits = g2 @ Wfuse + bfuse
    agg_kernel<<<NBUCK, 256, 0, stream>>>(B16, SB, srcBuck, bcur, dinv);
    gemm_kernel<<<gemmGrid, 256, 0, stream>>>(SB, params + PFW, SA, nullptr, params, dinv,
                                              PFB, 0, N_NODES);
    // postprocess
    post_kernel<<<(N_NODES + 3) / 4, 256, 0, stream>>>(SA, d_out, flags);
}

// Round 6
// 492.650 us; speedup vs baseline: 1.9451x; 1.1813x over previous
//
#include <hip/hip_runtime.h>
#include <hip/hip_bf16.h>
#include <math.h>

#define N_NODES 100000
#define N_EDGES 1600000
#define F 128
#define OUT_C 64
#define NUM_CLASSES 40
#define BN_EPS 1e-5f

#define NBUCK 782   // ceil(100000/128) buckets of 128 destination nodes
#define BCAP 4096   // per-bucket edge capacity
#define FILL_BLOCKS 128
#define EPB ((N_EDGES + FILL_BLOCKS - 1) / FILL_BLOCKS)  // 12500

typedef __hip_bfloat16 bf16;
typedef unsigned short ushort_t;
typedef __attribute__((ext_vector_type(8))) short bf16x8;
typedef __attribute__((ext_vector_type(4))) float f32x4;

// ---- fp32 param block offsets ----
#define PW1 0
#define PB1 16384
#define PW2 16512
#define PB2 32896
#define PGAMMA 33024
#define PBETA 33152
#define PMEAN 33280
#define PVAR 33408
#define PCLSW 33536
#define PCLSB 41728
#define PSIMW 41792
#define PSIMB 46912
#define PHOMW 46952
#define PHOMB 47080
#define PENTW 47081
#define PENTB 47209
#define PRAW_TOTAL 47210
#define PFW 47232
#define PFB 63616
#define PTOTAL 63744

__device__ __forceinline__ float uasf(unsigned u) { return __uint_as_float(u); }
__device__ __forceinline__ unsigned f2bu(float f) {
    bf16 h = __float2bfloat16(f);
    return (unsigned)*(unsigned short*)&h;
}

// ---------------- dtype detection ----------------
__global__ void detect_kernel(const void* __restrict__ x, const void* __restrict__ ei,
                              int* __restrict__ flags) {
    if (blockIdx.x != 0 || threadIdx.x != 0) return;
    const unsigned* xw = (const unsigned*)x;
    int votes = 0;
    for (int i = 0; i < 64; i++) {
        unsigned w = xw[i];
        unsigned e = (w >> 23) & 0xFFu;
        if (w == 0u || (e >= 90u && e <= 160u)) votes++;
    }
    flags[0] = (votes >= 48) ? 1 : 0;
    const unsigned* ew = (const unsigned*)ei;
    int zero_odd = 0;
    for (int i = 0; i < 64; i++)
        if (ew[2 * i + 1] == 0u) zero_odd++;
    flags[1] = (zero_odd >= 60) ? 1 : 0;
}

// ---------------- consolidated param convert ----------------
struct ParamSegs {
    const void* src[16];
    int dst[16];
};

__global__ void cvtparams_kernel(ParamSegs segs, float* __restrict__ params,
                                 const int* __restrict__ flags) {
    int idx = blockIdx.x * 256 + threadIdx.x;
    if (idx >= PRAW_TOTAL) return;
    int k = 0;
#pragma unroll
    for (int s = 1; s < 16; s++)
        if (idx >= segs.dst[s]) k = s;
    int rel = idx - segs.dst[k];
    const void* sp = segs.src[k];
    float v = flags[0] ? ((const float*)sp)[rel]
                       : __bfloat162float(((const bf16*)sp)[rel]);
    params[idx] = v;
}

// ---------------- edge load ----------------
__device__ __forceinline__ int load_edge(const int* __restrict__ ei, int which, int i, int i64) {
    size_t elem = (size_t)which * N_EDGES + (size_t)i;
    return i64 ? ei[elem * 2] : ei[elem];
}

// ---------------- fill: block-local LDS hist -> one reservation per (block,bucket) ----------
__global__ __launch_bounds__(256) void fill2_kernel(const int* __restrict__ ei,
                                                    int* __restrict__ bcur,
                                                    int* __restrict__ srcBuck,
                                                    const int* __restrict__ flags) {
    __shared__ int hist[NBUCK];
    __shared__ int gbase[NBUCK];
    __shared__ int lcur[NBUCK];
    int blk = blockIdx.x;
    int t = threadIdx.x;
    int i64 = flags[1];
    int e0 = blk * EPB;
    int ecnt = N_EDGES - e0;
    if (ecnt > EPB) ecnt = EPB;
    for (int i = t; i < NBUCK; i += 256) hist[i] = 0;
    __syncthreads();
    for (int i = t; i < ecnt; i += 256) {
        int c = load_edge(ei, 1, e0 + i, i64);
        atomicAdd(&hist[c >> 7], 1);
    }
    __syncthreads();
    for (int i = t; i < NBUCK; i += 256) {
        int c = hist[i];
        gbase[i] = (c > 0) ? atomicAdd(&bcur[i], c) : 0;
        lcur[i] = 0;
    }
    __syncthreads();
    for (int i = t; i < ecnt; i += 256) {
        int c = load_edge(ei, 1, e0 + i, i64);
        int r = load_edge(ei, 0, e0 + i, i64);
        int b = c >> 7;
        int p = gbase[b] + atomicAdd(&lcur[b], 1);
        if (p < BCAP) srcBuck[b * BCAP + p] = ((c & 127) << 17) | r;
    }
}

// ---------------- per-bucket degree count -> dinv ----------------
__global__ __launch_bounds__(256) void bucketcnt_kernel(const int* __restrict__ srcBuck,
                                                        const int* __restrict__ bcur,
                                                        float* __restrict__ dinv) {
    __shared__ int dcnt[128];
    int b = blockIdx.x;
    int t = threadIdx.x;
    if (t < 128) dcnt[t] = 0;
    __syncthreads();
    int cnt = bcur[b];
    if (cnt > BCAP) cnt = BCAP;
    for (int i = t; i < cnt; i += 256) atomicAdd(&dcnt[srcBuck[b * BCAP + i] >> 17], 1);
    __syncthreads();
    if (t < 128) {
        int n = (b << 7) + t;
        if (n < N_NODES) dinv[n] = rsqrtf((float)(dcnt[t] + 1));
    }
}

// ---------------- x -> bf16 prescaled by dinv ----------------
__global__ void cvtx_kernel(const void* __restrict__ x, const float* __restrict__ dinv,
                            unsigned short* __restrict__ B16, const int* __restrict__ flags) {
    int i4 = blockIdx.x * blockDim.x + threadIdx.x;
    if (i4 >= N_NODES * F / 4) return;
    int n = i4 >> 5;
    float d = dinv[n];
    float v0, v1, v2, v3;
    if (flags[0]) {
        float4 v = ((const float4*)x)[i4];
        v0 = v.x; v1 = v.y; v2 = v.z; v3 = v.w;
    } else {
        uint2 u = ((const uint2*)x)[i4];
        v0 = uasf(u.x << 16);
        v1 = uasf(u.x & 0xFFFF0000u);
        v2 = uasf(u.y << 16);
        v3 = uasf(u.y & 0xFFFF0000u);
    }
    uint2 o;
    o.x = f2bu(v0 * d) | (f2bu(v1 * d) << 16);
    o.y = f2bu(v2 * d) | (f2bu(v3 * d) << 16);
    ((uint2*)B16)[i4] = o;
}

// ---------------- fused W2 @ [cls|sim|hom|ent] precompute ----------------
__device__ __forceinline__ float headw(const float* __restrict__ p, int j, int c) {
    if (c < OUT_C) return p[PCLSW + j * OUT_C + c];
    if (c < OUT_C + NUM_CLASSES) return p[PSIMW + j * NUM_CLASSES + (c - OUT_C)];
    if (c == 104) return p[PHOMW + j];
    if (c == 105) return p[PENTW + j];
    return 0.f;
}

__global__ void fusew_kernel(float* __restrict__ params) {
    int idx = blockIdx.x * 256 + threadIdx.x;
    int k = idx >> 7;
    int c = idx & 127;
    float s = 0.f;
    for (int j = 0; j < 128; j++) s += params[PW2 + k * 128 + j] * headw(params, j, c);
    params[PFW + k * 128 + c] = s;
    if (k == 0) {
        float b = 0.f;
        for (int j = 0; j < 128; j++) b += params[PB2 + j] * headw(params, j, c);
        if (c < OUT_C) b += params[PCLSB + c];
        else if (c < OUT_C + NUM_CLASSES) b += params[PSIMB + c - OUT_C];
        else if (c == 104) b += params[PHOMB];
        else if (c == 105) b += params[PENTB];
        params[PFB + c] = b;
    }
}

// ---------------- W -> bf16 transposed (Wt[n*128+k] = W[k*128+n]) ----------------
__global__ void wcvt_kernel(const float* __restrict__ params, unsigned short* __restrict__ wt) {
    int idx = blockIdx.x * 256 + threadIdx.x;  // 32768
    if (idx >= 32768) return;
    int which = idx >> 14;
    int local = idx & 16383;
    int n = local >> 7;
    int k = local & 127;
    float v = params[(which ? PFW : PW1) + k * 128 + n];
    wt[(which << 14) + n * 128 + k] = (unsigned short)f2bu(v);
}

// ---------------- Aggregation: LDS counting sort per bucket + uint4 gather ----------------
#define ACC8(u)                                \
    do {                                       \
        a[0] += uasf((u).x << 16);             \
        a[1] += uasf((u).x & 0xFFFF0000u);     \
        a[2] += uasf((u).y << 16);             \
        a[3] += uasf((u).y & 0xFFFF0000u);     \
        a[4] += uasf((u).z << 16);             \
        a[5] += uasf((u).z & 0xFFFF0000u);     \
        a[6] += uasf((u).w << 16);             \
        a[7] += uasf((u).w & 0xFFFF0000u);     \
    } while (0)

__global__ __launch_bounds__(256) void agg_kernel(const unsigned short* __restrict__ B16,
                                                  unsigned short* __restrict__ G16,
                                                  const int* __restrict__ srcBuck,
                                                  const int* __restrict__ bcur,
                                                  const float* __restrict__ dinv) {
    __shared__ int raw[BCAP];
    __shared__ int sorted[BCAP];
    __shared__ int dcnt[128], doff[128], dcur[128];
    int b = blockIdx.x;
    int t = threadIdx.x;
    int cnt = bcur[b];
    if (cnt > BCAP) cnt = BCAP;
    if (t < 128) dcnt[t] = 0;
    __syncthreads();
    for (int i = t; i < cnt; i += 256) {
        int e = srcBuck[b * BCAP + i];
        raw[i] = e;
        atomicAdd(&dcnt[e >> 17], 1);
    }
    __syncthreads();
    if (t < 128) doff[t] = dcnt[t];
    __syncthreads();
    for (int d = 1; d < 128; d <<= 1) {
        int add = 0;
        if (t < 128 && t >= d) add = doff[t - d];
        __syncthreads();
        if (t < 128) doff[t] += add;
        __syncthreads();
    }
    if (t < 128) {
        doff[t] -= dcnt[t];
        dcur[t] = 0;
    }
    __syncthreads();
    for (int i = t; i < cnt; i += 256) {
        int e = raw[i];
        int d = e >> 17;
        int r = atomicAdd(&dcur[d], 1);
        sorted[doff[d] + r] = e & 0x1FFFF;
    }
    __syncthreads();

    int g16 = t >> 4;
    int hl8 = (t & 15) << 3;  // ushort offset within row
    int base = b << 7;
    for (int d = g16; d < 128; d += 16) {
        int n = base + d;
        if (n >= N_NODES) break;
        float a[8] = {0.f, 0.f, 0.f, 0.f, 0.f, 0.f, 0.f, 0.f};
        {
            uint4 u = *(const uint4*)(B16 + ((size_t)n << 7) + hl8);
            ACC8(u);
        }
        int o = doff[d], k = dcnt[d];
        int j = 0;
        for (; j + 4 <= k; j += 4) {
            int s0 = sorted[o + j];
            int s1 = sorted[o + j + 1];
            int s2 = sorted[o + j + 2];
            int s3 = sorted[o + j + 3];
            uint4 u0 = *(const uint4*)(B16 + ((size_t)s0 << 7) + hl8);
            uint4 u1 = *(const uint4*)(B16 + ((size_t)s1 << 7) + hl8);
            uint4 u2 = *(const uint4*)(B16 + ((size_t)s2 << 7) + hl8);
            uint4 u3 = *(const uint4*)(B16 + ((size_t)s3 << 7) + hl8);
            ACC8(u0);
            ACC8(u1);
            ACC8(u2);
            ACC8(u3);
        }
        for (; j < k; j++) {
            int s0 = sorted[o + j];
            uint4 u0 = *(const uint4*)(B16 + ((size_t)s0 << 7) + hl8);
            ACC8(u0);
        }
        float dn = dinv[n];
        uint4 pk;
        pk.x = f2bu(a[0] * dn) | (f2bu(a[1] * dn) << 16);
        pk.y = f2bu(a[2] * dn) | (f2bu(a[3] * dn) << 16);
        pk.z = f2bu(a[4] * dn) | (f2bu(a[5] * dn) << 16);
        pk.w = f2bu(a[6] * dn) | (f2bu(a[7] * dn) << 16);
        *(uint4*)(G16 + ((size_t)n << 7) + hl8) = pk;
    }
}

// ---------------- MFMA GEMM: [64 x 128] tile per block; mode1: BN+ReLU+prescale->bf16;
//                  mode0: fused heads postprocess -> d_out ----------------
#define LGPITCH 132

__global__ __launch_bounds__(256) void gemm_mfma_kernel(
    const unsigned short* __restrict__ A16, const unsigned short* __restrict__ Wt,
    unsigned short* __restrict__ outB, void* __restrict__ out,
    const float* __restrict__ params, const float* __restrict__ dinv, int mode,
    const int* __restrict__ flags) {
    __shared__ float Lg[64 * LGPITCH];
    __shared__ float sS[128], sO[128];
    int t = threadIdx.x;
    int wave = t >> 6, lane = t & 63, m16 = lane & 15, quad = lane >> 4;
    int blk = blockIdx.x;
    if (mode && t < 128) {
        float s = rsqrtf(params[PVAR + t] + BN_EPS) * params[PGAMMA + t];
        sS[t] = s;
        sO[t] = params[PB1 + t] * s + (params[PBETA + t] - params[PMEAN + t] * s);
    }
    int rowbase = blk * 64 + wave * 16;
    int rA = rowbase + m16;
    if (rA > N_NODES - 1) rA = N_NODES - 1;
    const size_t abase = (size_t)rA * 128 + (quad << 3);

    f32x4 acc[8];
#pragma unroll
    for (int ct = 0; ct < 8; ct++) acc[ct] = (f32x4){0.f, 0.f, 0.f, 0.f};

#pragma unroll
    for (int kk = 0; kk < 4; kk++) {
        bf16x8 af = *(const bf16x8*)(A16 + abase + kk * 32);
#pragma unroll
        for (int ct = 0; ct < 8; ct++) {
            bf16x8 bf = *(const bf16x8*)(Wt + (size_t)((ct * 16 + m16) * 128) + kk * 32 + (quad << 3));
            acc[ct] = __builtin_amdgcn_mfma_f32_16x16x32_bf16(af, bf, acc[ct], 0, 0, 0);
        }
    }
#pragma unroll
    for (int ct = 0; ct < 8; ct++)
#pragma unroll
        for (int reg = 0; reg < 4; reg++)
            Lg[(wave * 16 + quad * 4 + reg) * LGPITCH + ct * 16 + m16] = acc[ct][reg];
    __syncthreads();

    int r = t >> 2, sub = t & 3;
    int gr = blk * 64 + r;
    if (gr >= N_NODES) return;
    const float* row = &Lg[r * LGPITCH];

    if (mode) {
        float dn = dinv[gr];
        int c0 = sub * 32;
        unsigned pk[16];
#pragma unroll
        for (int i = 0; i < 16; i++) {
            int c = c0 + i * 2;
            float v0 = fmaxf(row[c] * sS[c] + sO[c], 0.f) * dn;
            float v1 = fmaxf(row[c + 1] * sS[c + 1] + sO[c + 1], 0.f) * dn;
            pk[i] = f2bu(v0) | (f2bu(v1) << 16);
        }
        uint4* dst = (uint4*)(outB + (size_t)gr * 128 + c0);
        dst[0] = make_uint4(pk[0], pk[1], pk[2], pk[3]);
        dst[1] = make_uint4(pk[4], pk[5], pk[6], pk[7]);
        dst[2] = make_uint4(pk[8], pk[9], pk[10], pk[11]);
        dst[3] = make_uint4(pk[12], pk[13], pk[14], pk[15]);
    } else {
        int isf = flags[0];
        const size_t OFF_SIM = (size_t)N_NODES * OUT_C;
        const size_t OFF_HOM = OFF_SIM + (size_t)N_NODES * NUM_CLASSES;
        const size_t OFF_ENT = OFF_HOM + (size_t)N_NODES;
        float* outf = (float*)out;
        bf16* outb = (bf16*)out;
#define STORE_OUT(idx, v)                        \
    do {                                         \
        if (isf) outf[(idx)] = (v);              \
        else outb[(idx)] = __float2bfloat16(v);  \
    } while (0)
        // cls log_softmax (cols 0..63), 16 per sub
        float lv[16];
        float m = -1e30f;
#pragma unroll
        for (int i = 0; i < 16; i++) {
            int c = sub * 16 + i;
            lv[i] = row[c] + params[PFB + c];
            m = fmaxf(m, lv[i]);
        }
        m = fmaxf(m, __shfl_xor(m, 1));
        m = fmaxf(m, __shfl_xor(m, 2));
        float S = 0.f;
#pragma unroll
        for (int i = 0; i < 16; i++) S += expf(lv[i] - m);
        S += __shfl_xor(S, 1);
        S += __shfl_xor(S, 2);
        float lS = logf(S) + m;
#pragma unroll
        for (int i = 0; i < 16; i++) STORE_OUT((size_t)gr * OUT_C + sub * 16 + i, lv[i] - lS);
        // sim softmax (cols 64..103), 10 per sub
        float sv[10];
        float m2 = -1e30f;
#pragma unroll
        for (int i = 0; i < 10; i++) {
            int c = OUT_C + sub * 10 + i;
            sv[i] = row[c] + params[PFB + c];
            m2 = fmaxf(m2, sv[i]);
        }
        m2 = fmaxf(m2, __shfl_xor(m2, 1));
        m2 = fmaxf(m2, __shfl_xor(m2, 2));
        float S2 = 0.f;
#pragma unroll
        for (int i = 0; i < 10; i++) {
            sv[i] = expf(sv[i] - m2);
            S2 += sv[i];
        }
        S2 += __shfl_xor(S2, 1);
        S2 += __shfl_xor(S2, 2);
        float rS2 = 1.f / S2;
#pragma unroll
        for (int i = 0; i < 10; i++)
            STORE_OUT(OFF_SIM + (size_t)gr * NUM_CLASSES + sub * 10 + i, sv[i] * rS2);
        if (sub == 0) {
            float hv = row[104] + params[PFB + 104];
            STORE_OUT(OFF_HOM + gr, 1.f / (1.f + expf(-hv)));
        }
        if (sub == 1) {
            float ev = row[105] + params[PFB + 105];
            STORE_OUT(OFF_ENT + gr, 1.f / (1.f + expf(-ev)));
        }
#undef STORE_OUT
    }
}

// ---------------- Launch ----------------
extern "C" void kernel_launch(void* const* d_in, const int* in_sizes, int n_in,
                              void* d_out, int out_size, void* d_ws, size_t ws_size,
                              hipStream_t stream) {
    const void* x = d_in[0];
    const int* ei = (const int*)d_in[1];

    char* ws = (char*)d_ws;
    size_t o = 0;
    auto alloc = [&](size_t bytes) {
        size_t r = o;
        o = (o + bytes + 255) & ~(size_t)255;
        return r;
    };
    char* RA = ws + alloc((size_t)51 * 1024 * 1024);   // srcBuck + B16
    char* RB = ws + alloc((size_t)26 * 1024 * 1024);   // G16
    float* params = (float*)(ws + alloc((size_t)PTOTAL * 4));
    unsigned short* wt = (unsigned short*)(ws + alloc(65536));
    float* dinv = (float*)(ws + alloc((size_t)N_NODES * 4));
    int* bcur = (int*)(ws + alloc((size_t)(NBUCK + 8) * 4));
    int* flags = (int*)(ws + alloc(256));

    int* srcBuck = (int*)RA;                                          // 12.81 MB
    unsigned short* B16 = (unsigned short*)(RA + 13u * 1024 * 1024);  // 25.6 MB
    unsigned short* G16 = (unsigned short*)RB;                        // 25.6 MB

    detect_kernel<<<1, 64, 0, stream>>>(x, ei, flags);
    hipMemsetAsync(bcur, 0, (size_t)(NBUCK + 8) * 4, stream);

    ParamSegs segs;
    const int srcIdx[16] = {2, 3, 4, 5, 6, 7, 8, 9, 10, 11, 12, 13, 14, 15, 16, 17};
    const int dsts[16] = {PW1, PB1, PW2, PB2, PGAMMA, PBETA, PMEAN, PVAR,
                          PCLSW, PCLSB, PSIMW, PSIMB, PHOMW, PHOMB, PENTW, PENTB};
    for (int k = 0; k < 16; k++) {
        segs.src[k] = d_in[srcIdx[k]];
        segs.dst[k] = dsts[k];
    }
    cvtparams_kernel<<<(PRAW_TOTAL + 255) / 256, 256, 0, stream>>>(segs, params, flags);
    fusew_kernel<<<64, 256, 0, stream>>>(params);
    wcvt_kernel<<<128, 256, 0, stream>>>(params, wt);

    fill2_kernel<<<FILL_BLOCKS, 256, 0, stream>>>(ei, bcur, srcBuck, flags);
    bucketcnt_kernel<<<NBUCK, 256, 0, stream>>>(srcBuck, bcur, dinv);
    cvtx_kernel<<<(N_NODES * F / 4 + 255) / 256, 256, 0, stream>>>(x, dinv, B16, flags);

    const int gemmGrid = (N_NODES + 63) / 64;

    // layer 1: g1 = A_hat x ; h1 = bf16(ReLU(BN(g1 @ W1 + b1)) * dinv)
    agg_kernel<<<NBUCK, 256, 0, stream>>>(B16, G16, srcBuck, bcur, dinv);
    gemm_mfma_kernel<<<gemmGrid, 256, 0, stream>>>(G16, wt, B16, nullptr, params, dinv, 1, flags);
    // layer 2 + fused heads + post: g2 = A_hat h1 ; out = post(g2 @ Wfuse + bfuse)
    agg_kernel<<<NBUCK, 256, 0, stream>>>(B16, G16, srcBuck, bcur, dinv);
    gemm_mfma_kernel<<<gemmGrid, 256, 0, stream>>>(G16, wt + 16384, nullptr, d_out, params, dinv, 0, flags);
}

// Round 7
// 462.938 us; speedup vs baseline: 2.0699x; 1.0642x over previous
//
#include <hip/hip_runtime.h>
#include <hip/hip_bf16.h>
#include <math.h>

#define N_NODES 100000
#define N_EDGES 1600000
#define F 128
#define OUT_C 64
#define NUM_CLASSES 40
#define BN_EPS 1e-5f

#define NBUCK 782   // ceil(100000/128) buckets of 128 destination nodes
#define BCAP 4096   // per-bucket edge capacity
#define FILL_BLOCKS 128
#define EPB ((N_EDGES + FILL_BLOCKS - 1) / FILL_BLOCKS)  // 12500

typedef __hip_bfloat16 bf16;
typedef __attribute__((ext_vector_type(8))) short bf16x8;
typedef __attribute__((ext_vector_type(4))) float f32x4;

// ---- fp32 param block offsets ----
#define PW1 0
#define PB1 16384
#define PW2 16512
#define PB2 32896
#define PGAMMA 33024
#define PBETA 33152
#define PMEAN 33280
#define PVAR 33408
#define PCLSW 33536
#define PCLSB 41728
#define PSIMW 41792
#define PSIMB 46912
#define PHOMW 46952
#define PHOMB 47080
#define PENTW 47081
#define PENTB 47209
#define PRAW_TOTAL 47210
#define PFW 47232
#define PFB 63616
#define PTOTAL 63744

__device__ __forceinline__ float uasf(unsigned u) { return __uint_as_float(u); }
__device__ __forceinline__ unsigned f2bu(float f) {
    bf16 h = __float2bfloat16(f);
    return (unsigned)*(unsigned short*)&h;
}

// ---------------- dtype detection ----------------
__global__ void detect_kernel(const void* __restrict__ x, const void* __restrict__ ei,
                              int* __restrict__ flags) {
    if (blockIdx.x != 0 || threadIdx.x != 0) return;
    const unsigned* xw = (const unsigned*)x;
    int votes = 0;
    for (int i = 0; i < 64; i++) {
        unsigned w = xw[i];
        unsigned e = (w >> 23) & 0xFFu;
        if (w == 0u || (e >= 90u && e <= 160u)) votes++;
    }
    flags[0] = (votes >= 48) ? 1 : 0;
    const unsigned* ew = (const unsigned*)ei;
    int zero_odd = 0;
    for (int i = 0; i < 64; i++)
        if (ew[2 * i + 1] == 0u) zero_odd++;
    flags[1] = (zero_odd >= 60) ? 1 : 0;
}

// ---------------- consolidated param convert ----------------
struct ParamSegs {
    const void* src[16];
    int dst[16];
};

__global__ void cvtparams_kernel(ParamSegs segs, float* __restrict__ params,
                                 const int* __restrict__ flags) {
    int idx = blockIdx.x * 256 + threadIdx.x;
    if (idx >= PRAW_TOTAL) return;
    int k = 0;
#pragma unroll
    for (int s = 1; s < 16; s++)
        if (idx >= segs.dst[s]) k = s;
    int rel = idx - segs.dst[k];
    const void* sp = segs.src[k];
    float v = flags[0] ? ((const float*)sp)[rel]
                       : __bfloat162float(((const bf16*)sp)[rel]);
    params[idx] = v;
}

// ---------------- edge load ----------------
__device__ __forceinline__ int load_edge(const int* __restrict__ ei, int which, int i, int i64) {
    size_t elem = (size_t)which * N_EDGES + (size_t)i;
    return i64 ? ei[elem * 2] : ei[elem];
}

// ---------------- fill: block-local LDS hist -> one reservation per (block,bucket) ----------
__global__ __launch_bounds__(256) void fill2_kernel(const int* __restrict__ ei,
                                                    int* __restrict__ bcur,
                                                    int* __restrict__ srcBuck,
                                                    const int* __restrict__ flags) {
    __shared__ int hist[NBUCK];
    __shared__ int gbase[NBUCK];
    __shared__ int lcur[NBUCK];
    int blk = blockIdx.x;
    int t = threadIdx.x;
    int i64 = flags[1];
    int e0 = blk * EPB;
    int ecnt = N_EDGES - e0;
    if (ecnt > EPB) ecnt = EPB;
    for (int i = t; i < NBUCK; i += 256) hist[i] = 0;
    __syncthreads();
    for (int i = t; i < ecnt; i += 256) {
        int c = load_edge(ei, 1, e0 + i, i64);
        atomicAdd(&hist[c >> 7], 1);
    }
    __syncthreads();
    for (int i = t; i < NBUCK; i += 256) {
        int c = hist[i];
        gbase[i] = (c > 0) ? atomicAdd(&bcur[i], c) : 0;
        lcur[i] = 0;
    }
    __syncthreads();
    for (int i = t; i < ecnt; i += 256) {
        int c = load_edge(ei, 1, e0 + i, i64);
        int r = load_edge(ei, 0, e0 + i, i64);
        int b = c >> 7;
        int p = gbase[b] + atomicAdd(&lcur[b], 1);
        if (p < BCAP) srcBuck[b * BCAP + p] = ((c & 127) << 17) | r;
    }
}

// ---------------- per-bucket degree count -> dinv ----------------
__global__ __launch_bounds__(256) void bucketcnt_kernel(const int* __restrict__ srcBuck,
                                                        const int* __restrict__ bcur,
                                                        float* __restrict__ dinv) {
    __shared__ int dcnt[128];
    int b = blockIdx.x;
    int t = threadIdx.x;
    if (t < 128) dcnt[t] = 0;
    __syncthreads();
    int cnt = bcur[b];
    if (cnt > BCAP) cnt = BCAP;
    for (int i = t; i < cnt; i += 256) atomicAdd(&dcnt[srcBuck[b * BCAP + i] >> 17], 1);
    __syncthreads();
    if (t < 128) {
        int n = (b << 7) + t;
        if (n < N_NODES) dinv[n] = rsqrtf((float)(dcnt[t] + 1));
    }
}

// ---------------- x -> bf16 prescaled by dinv ----------------
__global__ void cvtx_kernel(const void* __restrict__ x, const float* __restrict__ dinv,
                            unsigned short* __restrict__ B16, const int* __restrict__ flags) {
    int i4 = blockIdx.x * blockDim.x + threadIdx.x;
    if (i4 >= N_NODES * F / 4) return;
    int n = i4 >> 5;
    float d = dinv[n];
    float v0, v1, v2, v3;
    if (flags[0]) {
        float4 v = ((const float4*)x)[i4];
        v0 = v.x; v1 = v.y; v2 = v.z; v3 = v.w;
    } else {
        uint2 u = ((const uint2*)x)[i4];
        v0 = uasf(u.x << 16);
        v1 = uasf(u.x & 0xFFFF0000u);
        v2 = uasf(u.y << 16);
        v3 = uasf(u.y & 0xFFFF0000u);
    }
    uint2 o;
    o.x = f2bu(v0 * d) | (f2bu(v1 * d) << 16);
    o.y = f2bu(v2 * d) | (f2bu(v3 * d) << 16);
    ((uint2*)B16)[i4] = o;
}

// ---------------- fused W2 @ [cls|sim|hom|ent] precompute ----------------
__device__ __forceinline__ float headw(const float* __restrict__ p, int j, int c) {
    if (c < OUT_C) return p[PCLSW + j * OUT_C + c];
    if (c < OUT_C + NUM_CLASSES) return p[PSIMW + j * NUM_CLASSES + (c - OUT_C)];
    if (c == 104) return p[PHOMW + j];
    if (c == 105) return p[PENTW + j];
    return 0.f;
}

__global__ void fusew_kernel(float* __restrict__ params) {
    int idx = blockIdx.x * 256 + threadIdx.x;
    int k = idx >> 7;
    int c = idx & 127;
    float s = 0.f;
    for (int j = 0; j < 128; j++) s += params[PW2 + k * 128 + j] * headw(params, j, c);
    params[PFW + k * 128 + c] = s;
    if (k == 0) {
        float b = 0.f;
        for (int j = 0; j < 128; j++) b += params[PB2 + j] * headw(params, j, c);
        if (c < OUT_C) b += params[PCLSB + c];
        else if (c < OUT_C + NUM_CLASSES) b += params[PSIMB + c - OUT_C];
        else if (c == 104) b += params[PHOMB];
        else if (c == 105) b += params[PENTB];
        params[PFB + c] = b;
    }
}

// ---------------- W -> bf16 transposed ----------------
// wt1[n*128+k]  = W1[k][n]                      (k = true col of layer-1 input)
// wt2[n*128+p]  = Wfuse[colOf(p)][n]            (p = permuted position of h1 storage)
// colOf(p) = (p&7)*16 + (p>>3)   [inverse of p(c) = (c&15)*8 + (c>>4)]
__global__ void wcvt_kernel(const float* __restrict__ params, unsigned short* __restrict__ wt) {
    int idx = blockIdx.x * 256 + threadIdx.x;  // 32768
    if (idx >= 32768) return;
    int which = idx >> 14;
    int local = idx & 16383;
    int n = local >> 7;
    int k = local & 127;
    int ksrc = which ? ((k & 7) * 16 + (k >> 3)) : k;
    float v = params[(which ? PFW : PW1) + ksrc * 128 + n];
    wt[(which << 14) + n * 128 + k] = (unsigned short)f2bu(v);
}

// ---------------- Aggregation: LDS counting sort per bucket + uint4 gather ----------------
#define ACC8(u)                                \
    do {                                       \
        a[0] += uasf((u).x << 16);             \
        a[1] += uasf((u).x & 0xFFFF0000u);     \
        a[2] += uasf((u).y << 16);             \
        a[3] += uasf((u).y & 0xFFFF0000u);     \
        a[4] += uasf((u).z << 16);             \
        a[5] += uasf((u).z & 0xFFFF0000u);     \
        a[6] += uasf((u).w << 16);             \
        a[7] += uasf((u).w & 0xFFFF0000u);     \
    } while (0)

__global__ __launch_bounds__(256) void agg_kernel(const unsigned short* __restrict__ B16,
                                                  unsigned short* __restrict__ G16,
                                                  const int* __restrict__ srcBuck,
                                                  const int* __restrict__ bcur,
                                                  const float* __restrict__ dinv) {
    __shared__ int raw[BCAP];
    __shared__ int sorted[BCAP];
    __shared__ int dcnt[128], doff[128], dcur[128];
    int b = blockIdx.x;
    int t = threadIdx.x;
    int cnt = bcur[b];
    if (cnt > BCAP) cnt = BCAP;
    if (t < 128) dcnt[t] = 0;
    __syncthreads();
    for (int i = t; i < cnt; i += 256) {
        int e = srcBuck[b * BCAP + i];
        raw[i] = e;
        atomicAdd(&dcnt[e >> 17], 1);
    }
    __syncthreads();
    if (t < 128) doff[t] = dcnt[t];
    __syncthreads();
    for (int d = 1; d < 128; d <<= 1) {
        int add = 0;
        if (t < 128 && t >= d) add = doff[t - d];
        __syncthreads();
        if (t < 128) doff[t] += add;
        __syncthreads();
    }
    if (t < 128) {
        doff[t] -= dcnt[t];
        dcur[t] = 0;
    }
    __syncthreads();
    for (int i = t; i < cnt; i += 256) {
        int e = raw[i];
        int d = e >> 17;
        int r = atomicAdd(&dcur[d], 1);
        sorted[doff[d] + r] = e & 0x1FFFF;
    }
    __syncthreads();

    int g16 = t >> 4;
    int hl8 = (t & 15) << 3;
    int base = b << 7;
    for (int d = g16; d < 128; d += 16) {
        int n = base + d;
        if (n >= N_NODES) break;
        float a[8] = {0.f, 0.f, 0.f, 0.f, 0.f, 0.f, 0.f, 0.f};
        {
            uint4 u = *(const uint4*)(B16 + ((size_t)n << 7) + hl8);
            ACC8(u);
        }
        int o = doff[d], k = dcnt[d];
        int j = 0;
        for (; j + 4 <= k; j += 4) {
            int s0 = sorted[o + j];
            int s1 = sorted[o + j + 1];
            int s2 = sorted[o + j + 2];
            int s3 = sorted[o + j + 3];
            uint4 u0 = *(const uint4*)(B16 + ((size_t)s0 << 7) + hl8);
            uint4 u1 = *(const uint4*)(B16 + ((size_t)s1 << 7) + hl8);
            uint4 u2 = *(const uint4*)(B16 + ((size_t)s2 << 7) + hl8);
            uint4 u3 = *(const uint4*)(B16 + ((size_t)s3 << 7) + hl8);
            ACC8(u0);
            ACC8(u1);
            ACC8(u2);
            ACC8(u3);
        }
        for (; j < k; j++) {
            int s0 = sorted[o + j];
            uint4 u0 = *(const uint4*)(B16 + ((size_t)s0 << 7) + hl8);
            ACC8(u0);
        }
        float dn = dinv[n];
        uint4 pk;
        pk.x = f2bu(a[0] * dn) | (f2bu(a[1] * dn) << 16);
        pk.y = f2bu(a[2] * dn) | (f2bu(a[3] * dn) << 16);
        pk.z = f2bu(a[4] * dn) | (f2bu(a[5] * dn) << 16);
        pk.w = f2bu(a[6] * dn) | (f2bu(a[7] * dn) << 16);
        *(uint4*)(G16 + ((size_t)n << 7) + hl8) = pk;
    }
}

// ---------------- MFMA GEMM, no LDS transpose: permuted-column output storage ------------
// Lane (m16, quad) after 32 MFMAs holds C[row = quad*4+reg][col = ct*16+m16], ct=0..7.
// mode1: h = bf16(ReLU(BN(C+b1))*dinv) stored at position p = m16*8+ct  -> uint4/row, coalesced.
// mode0: heads post fully in-register (row spread over 16 lanes x 8 regs; shfl_xor 1/2/4/8).
__global__ __launch_bounds__(256) void gemm_mfma_kernel(
    const unsigned short* __restrict__ A16, const unsigned short* __restrict__ Wt,
    unsigned short* __restrict__ outB, void* __restrict__ out,
    const float* __restrict__ params, const float* __restrict__ dinv, int mode,
    const int* __restrict__ flags) {
    __shared__ float sS[128], sO[128], sFB[128];
    int t = threadIdx.x;
    if (t < 128) {
        if (mode) {
            float s = rsqrtf(params[PVAR + t] + BN_EPS) * params[PGAMMA + t];
            sS[t] = s;
            sO[t] = params[PB1 + t] * s + (params[PBETA + t] - params[PMEAN + t] * s);
        } else {
            sFB[t] = params[PFB + t];
        }
    }
    __syncthreads();
    int wave = t >> 6, lane = t & 63, m16 = lane & 15, quad = lane >> 4;
    int rowbase = blockIdx.x * 64 + wave * 16;
    int rA = rowbase + m16;
    if (rA >= N_NODES) rA = N_NODES - 1;
    const size_t abase = (size_t)rA * 128 + (quad << 3);

    f32x4 acc[8];
#pragma unroll
    for (int ct = 0; ct < 8; ct++) acc[ct] = (f32x4){0.f, 0.f, 0.f, 0.f};

#pragma unroll
    for (int kk = 0; kk < 4; kk++) {
        bf16x8 af = *(const bf16x8*)(A16 + abase + kk * 32);
#pragma unroll
        for (int ct = 0; ct < 8; ct++) {
            bf16x8 bf = *(const bf16x8*)(Wt + (size_t)((ct * 16 + m16) * 128) + kk * 32 + (quad << 3));
            acc[ct] = __builtin_amdgcn_mfma_f32_16x16x32_bf16(af, bf, acc[ct], 0, 0, 0);
        }
    }

    int r0 = rowbase + quad * 4;
    if (mode) {
        float sc[8], of[8];
#pragma unroll
        for (int ct = 0; ct < 8; ct++) {
            sc[ct] = sS[ct * 16 + m16];
            of[ct] = sO[ct * 16 + m16];
        }
#pragma unroll
        for (int reg = 0; reg < 4; reg++) {
            int gr = r0 + reg;
            if (gr >= N_NODES) continue;
            float dn = dinv[gr];
            unsigned pk[4];
#pragma unroll
            for (int i = 0; i < 4; i++) {
                float v0 = fmaxf(acc[2 * i][reg] * sc[2 * i] + of[2 * i], 0.f) * dn;
                float v1 = fmaxf(acc[2 * i + 1][reg] * sc[2 * i + 1] + of[2 * i + 1], 0.f) * dn;
                pk[i] = f2bu(v0) | (f2bu(v1) << 16);
            }
            *(uint4*)(outB + (size_t)gr * 128 + (m16 << 3)) = make_uint4(pk[0], pk[1], pk[2], pk[3]);
        }
    } else {
        int isf = flags[0];
        const size_t OFF_SIM = (size_t)N_NODES * OUT_C;
        const size_t OFF_HOM = OFF_SIM + (size_t)N_NODES * NUM_CLASSES;
        const size_t OFF_ENT = OFF_HOM + (size_t)N_NODES;
        float* outf = (float*)out;
        bf16* outb = (bf16*)out;
        float fb[8];
#pragma unroll
        for (int ct = 0; ct < 8; ct++) fb[ct] = sFB[ct * 16 + m16];
#define STORE_OUT(idx, v)                        \
    do {                                         \
        if (isf) outf[(idx)] = (v);              \
        else outb[(idx)] = __float2bfloat16(v);  \
    } while (0)
#pragma unroll
        for (int reg = 0; reg < 4; reg++) {
            int gr = r0 + reg;
            bool vrow = (gr < N_NODES);
            float v[8];
#pragma unroll
            for (int ct = 0; ct < 8; ct++) v[ct] = acc[ct][reg] + fb[ct];
            // cls log_softmax over cols 0..63 (ct 0..3)
            float m = fmaxf(fmaxf(v[0], v[1]), fmaxf(v[2], v[3]));
            m = fmaxf(m, __shfl_xor(m, 1));
            m = fmaxf(m, __shfl_xor(m, 2));
            m = fmaxf(m, __shfl_xor(m, 4));
            m = fmaxf(m, __shfl_xor(m, 8));
            float S = expf(v[0] - m) + expf(v[1] - m) + expf(v[2] - m) + expf(v[3] - m);
            S += __shfl_xor(S, 1);
            S += __shfl_xor(S, 2);
            S += __shfl_xor(S, 4);
            S += __shfl_xor(S, 8);
            float lS = m + logf(S);
            if (vrow) {
#pragma unroll
                for (int ct = 0; ct < 4; ct++)
                    STORE_OUT((size_t)gr * OUT_C + ct * 16 + m16, v[ct] - lS);
            }
            // sim softmax over cols 64..103 (ct 4,5 all lanes; ct 6 iff m16<8)
            bool has6 = (m16 < 8);
            float s4 = v[4], s5 = v[5], s6 = has6 ? v[6] : -INFINITY;
            float m2 = fmaxf(fmaxf(s4, s5), s6);
            m2 = fmaxf(m2, __shfl_xor(m2, 1));
            m2 = fmaxf(m2, __shfl_xor(m2, 2));
            m2 = fmaxf(m2, __shfl_xor(m2, 4));
            m2 = fmaxf(m2, __shfl_xor(m2, 8));
            float e4 = expf(s4 - m2), e5 = expf(s5 - m2), e6 = has6 ? expf(s6 - m2) : 0.f;
            float S2 = e4 + e5 + e6;
            S2 += __shfl_xor(S2, 1);
            S2 += __shfl_xor(S2, 2);
            S2 += __shfl_xor(S2, 4);
            S2 += __shfl_xor(S2, 8);
            float rS2 = 1.f / S2;
            if (vrow) {
                STORE_OUT(OFF_SIM + (size_t)gr * NUM_CLASSES + m16, e4 * rS2);
                STORE_OUT(OFF_SIM + (size_t)gr * NUM_CLASSES + 16 + m16, e5 * rS2);
                if (has6) STORE_OUT(OFF_SIM + (size_t)gr * NUM_CLASSES + 32 + m16, e6 * rS2);
                if (m16 == 8) STORE_OUT(OFF_HOM + gr, 1.f / (1.f + expf(-v[6])));
                if (m16 == 9) STORE_OUT(OFF_ENT + gr, 1.f / (1.f + expf(-v[6])));
            }
        }
#undef STORE_OUT
    }
}

// ---------------- Launch ----------------
extern "C" void kernel_launch(void* const* d_in, const int* in_sizes, int n_in,
                              void* d_out, int out_size, void* d_ws, size_t ws_size,
                              hipStream_t stream) {
    const void* x = d_in[0];
    const int* ei = (const int*)d_in[1];

    char* ws = (char*)d_ws;
    size_t o = 0;
    auto alloc = [&](size_t bytes) {
        size_t r = o;
        o = (o + bytes + 255) & ~(size_t)255;
        return r;
    };
    char* RA = ws + alloc((size_t)51 * 1024 * 1024);   // srcBuck + B16
    char* RB = ws + alloc((size_t)26 * 1024 * 1024);   // G16
    float* params = (float*)(ws + alloc((size_t)PTOTAL * 4));
    unsigned short* wt = (unsigned short*)(ws + alloc(65536));
    float* dinv = (float*)(ws + alloc((size_t)N_NODES * 4));
    int* bcur = (int*)(ws + alloc((size_t)(NBUCK + 8) * 4));
    int* flags = (int*)(ws + alloc(256));

    int* srcBuck = (int*)RA;                                          // 12.81 MB
    unsigned short* B16 = (unsigned short*)(RA + 13u * 1024 * 1024);  // 25.6 MB
    unsigned short* G16 = (unsigned short*)RB;                        // 25.6 MB

    detect_kernel<<<1, 64, 0, stream>>>(x, ei, flags);
    hipMemsetAsync(bcur, 0, (size_t)(NBUCK + 8) * 4, stream);

    ParamSegs segs;
    const int srcIdx[16] = {2, 3, 4, 5, 6, 7, 8, 9, 10, 11, 12, 13, 14, 15, 16, 17};
    const int dsts[16] = {PW1, PB1, PW2, PB2, PGAMMA, PBETA, PMEAN, PVAR,
                          PCLSW, PCLSB, PSIMW, PSIMB, PHOMW, PHOMB, PENTW, PENTB};
    for (int k = 0; k < 16; k++) {
        segs.src[k] = d_in[srcIdx[k]];
        segs.dst[k] = dsts[k];
    }
    cvtparams_kernel<<<(PRAW_TOTAL + 255) / 256, 256, 0, stream>>>(segs, params, flags);
    fusew_kernel<<<64, 256, 0, stream>>>(params);
    wcvt_kernel<<<128, 256, 0, stream>>>(params, wt);

    fill2_kernel<<<FILL_BLOCKS, 256, 0, stream>>>(ei, bcur, srcBuck, flags);
    bucketcnt_kernel<<<NBUCK, 256, 0, stream>>>(srcBuck, bcur, dinv);
    cvtx_kernel<<<(N_NODES * F / 4 + 255) / 256, 256, 0, stream>>>(x, dinv, B16, flags);

    const int gemmGrid = (N_NODES + 63) / 64;

    // layer 1: g1 = A_hat x ; h1 = bf16(ReLU(BN(g1 @ W1 + b1)) * dinv)  [permuted cols]
    agg_kernel<<<NBUCK, 256, 0, stream>>>(B16, G16, srcBuck, bcur, dinv);
    gemm_mfma_kernel<<<gemmGrid, 256, 0, stream>>>(G16, wt, B16, nullptr, params, dinv, 1, flags);
    // layer 2 + fused heads + post: g2 = A_hat h1 ; out = post(g2 @ Wfuse' + bfuse)
    agg_kernel<<<NBUCK, 256, 0, stream>>>(B16, G16, srcBuck, bcur, dinv);
    gemm_mfma_kernel<<<gemmGrid, 256, 0, stream>>>(G16, wt + 16384, nullptr, d_out, params, dinv, 0, flags);
}